// Round 1
// baseline (402.175 us; speedup 1.0000x reference)
//
#include <hip/hip_runtime.h>

// BackWarp: dense bilinear backward warp.
// image: [B,H,W,C] f32, flow: [B,H,W,2] f32, out: [B,H,W,C] f32
// query = (y,x) - flow; bilinear sample of image at query with boundary clamp:
//   fy = clip(floor(qy), 0, H-2); ay = clip(qy - fy, 0, 1)   (same for x)

#define BW_B 16
#define BW_H 720
#define BW_W 1280
#define BW_C 3

__global__ __launch_bounds__(256) void backwarp_kernel(
    const float* __restrict__ image,
    const float* __restrict__ flow,
    float* __restrict__ out) {
    const int idx = blockIdx.x * blockDim.x + threadIdx.x;  // pixel index over B*H*W
    const int total = BW_B * BW_H * BW_W;
    if (idx >= total) return;

    const int x = idx % BW_W;
    const int t = idx / BW_W;
    const int y = t % BW_H;
    const int b = t / BW_H;

    // coalesced 8B flow load
    const float2 f = reinterpret_cast<const float2*>(flow)[idx];
    const float qy = (float)y - f.x;
    const float qx = (float)x - f.y;

    float fy = floorf(qy);
    fy = fminf(fmaxf(fy, 0.0f), (float)(BW_H - 2));
    float fx = floorf(qx);
    fx = fminf(fmaxf(fx, 0.0f), (float)(BW_W - 2));
    const float ay = fminf(fmaxf(qy - fy, 0.0f), 1.0f);
    const float ax = fminf(fmaxf(qx - fx, 0.0f), 1.0f);
    const int iy = (int)fy;
    const int ix = (int)fx;

    // gather 4 neighbors x 3 channels (flow ~ N(0,1) -> near-identity, cache-friendly)
    const float* __restrict__ p0 =
        image + ((b * BW_H + iy) * BW_W + ix) * BW_C;      // top-left
    const float* __restrict__ p1 = p0 + BW_W * BW_C;       // bottom-left

    const float tl0 = p0[0], tl1 = p0[1], tl2 = p0[2];
    const float tr0 = p0[3], tr1 = p0[4], tr2 = p0[5];
    const float bl0 = p1[0], bl1 = p1[1], bl2 = p1[2];
    const float br0 = p1[3], br1 = p1[4], br2 = p1[5];

    // interp_top = tl + ax*(tr-tl); interp_bottom = bl + ax*(br-bl);
    // out = interp_top + ay*(interp_bottom - interp_top)
    const float it0 = tl0 + ax * (tr0 - tl0);
    const float it1 = tl1 + ax * (tr1 - tl1);
    const float it2 = tl2 + ax * (tr2 - tl2);
    const float ib0 = bl0 + ax * (br0 - bl0);
    const float ib1 = bl1 + ax * (br1 - bl1);
    const float ib2 = bl2 + ax * (br2 - bl2);

    float* __restrict__ o = out + idx * BW_C;
    o[0] = it0 + ay * (ib0 - it0);
    o[1] = it1 + ay * (ib1 - it1);
    o[2] = it2 + ay * (ib2 - it2);
}

extern "C" void kernel_launch(void* const* d_in, const int* in_sizes, int n_in,
                              void* d_out, int out_size, void* d_ws, size_t ws_size,
                              hipStream_t stream) {
    const float* image = (const float*)d_in[0];
    const float* flow  = (const float*)d_in[1];
    float* out = (float*)d_out;

    const int total = BW_B * BW_H * BW_W;  // 14,745,600 pixels
    const int block = 256;
    const int grid = (total + block - 1) / block;  // 57,600 blocks
    backwarp_kernel<<<grid, block, 0, stream>>>(image, flow, out);
}

// Round 2
// 371.415 us; speedup vs baseline: 1.0828x; 1.0828x over previous
//
#include <hip/hip_runtime.h>

// BackWarp: dense bilinear backward warp, 2D-tiled for image-row reuse.
// image: [B,H,W,C] f32, flow: [B,H,W,2] f32, out: [B,H,W,C] f32
// query = (y,x) - flow; bilinear with boundary clamp:
//   fy = clip(floor(qy), 0, H-2); ay = clip(qy - fy, 0, 1)   (same for x)
//
// Block = 256 threads as (64 x, 4 y); each thread does rows ty and ty+4 of a
// 64x8 tile -> vertical row reuse stays in-cache within the block, and each
// thread has 2 independent gather chains (latency hiding).

#define BW_B 16
#define BW_H 720
#define BW_W 1280
#define BW_C 3

#define TILE_W 64
#define TILE_H 8

__device__ __forceinline__ void warp_one(
    const float* __restrict__ imgb,  // image base for this batch
    float2 f, int x, int y, float* __restrict__ o) {
    const float qy = (float)y - f.x;
    const float qx = (float)x - f.y;

    float fy = floorf(qy);
    fy = fminf(fmaxf(fy, 0.0f), (float)(BW_H - 2));
    float fx = floorf(qx);
    fx = fminf(fmaxf(fx, 0.0f), (float)(BW_W - 2));
    const float ay = fminf(fmaxf(qy - fy, 0.0f), 1.0f);
    const float ax = fminf(fmaxf(qx - fx, 0.0f), 1.0f);
    const int iy = (int)fy;
    const int ix = (int)fx;

    const float* __restrict__ p0 = imgb + (iy * BW_W + ix) * BW_C;  // top-left
    const float* __restrict__ p1 = p0 + BW_W * BW_C;                // bottom-left

    const float tl0 = p0[0], tl1 = p0[1], tl2 = p0[2];
    const float tr0 = p0[3], tr1 = p0[4], tr2 = p0[5];
    const float bl0 = p1[0], bl1 = p1[1], bl2 = p1[2];
    const float br0 = p1[3], br1 = p1[4], br2 = p1[5];

    const float it0 = tl0 + ax * (tr0 - tl0);
    const float it1 = tl1 + ax * (tr1 - tl1);
    const float it2 = tl2 + ax * (tr2 - tl2);
    const float ib0 = bl0 + ax * (br0 - bl0);
    const float ib1 = bl1 + ax * (br1 - bl1);
    const float ib2 = bl2 + ax * (br2 - bl2);

    __builtin_nontemporal_store(it0 + ay * (ib0 - it0), o + 0);
    __builtin_nontemporal_store(it1 + ay * (ib1 - it1), o + 1);
    __builtin_nontemporal_store(it2 + ay * (ib2 - it2), o + 2);
}

__global__ __launch_bounds__(256) void backwarp_kernel(
    const float* __restrict__ image,
    const float* __restrict__ flow,
    float* __restrict__ out) {
    const int x = blockIdx.x * TILE_W + threadIdx.x;          // [0, W)
    const int y0 = blockIdx.y * TILE_H + threadIdx.y;         // rows ty and ty+4
    const int y1 = y0 + 4;
    const int b = blockIdx.z;

    const float* __restrict__ imgb = image + (size_t)b * BW_H * BW_W * BW_C;
    const size_t base_b = (size_t)b * BW_H * BW_W;

    const size_t i0 = base_b + (size_t)y0 * BW_W + x;
    const size_t i1 = base_b + (size_t)y1 * BW_W + x;

    // coalesced 8B flow loads (2 independent pixels -> 2 gather chains in flight)
    const float2 f0 = reinterpret_cast<const float2*>(flow)[i0];
    const float2 f1 = reinterpret_cast<const float2*>(flow)[i1];

    warp_one(imgb, f0, x, y0, out + i0 * BW_C);
    warp_one(imgb, f1, x, y1, out + i1 * BW_C);
}

extern "C" void kernel_launch(void* const* d_in, const int* in_sizes, int n_in,
                              void* d_out, int out_size, void* d_ws, size_t ws_size,
                              hipStream_t stream) {
    const float* image = (const float*)d_in[0];
    const float* flow  = (const float*)d_in[1];
    float* out = (float*)d_out;

    dim3 block(TILE_W, TILE_H / 2, 1);                       // 64 x 4 = 256
    dim3 grid(BW_W / TILE_W, BW_H / TILE_H, BW_B);           // 20 x 90 x 16
    backwarp_kernel<<<grid, block, 0, stream>>>(image, flow, out);
}